// Round 1
// baseline (7360.544 us; speedup 1.0000x reference)
//
#include <hip/hip_runtime.h>
#include <math.h>

#define BB 4
#define SS 2048
#define DD 768
#define HH 12
#define KK 64
#define TS 8

// ---------------------------------------------------------------------------
// QKV projection: qkv[proj][b][h][s][k] = sum_d x[b][s][d] * W[proj][h][d][k]
// One block per (proj, b, 8-row s-tile). 768 threads = (h,k) pairs.
// x rows staged in LDS; each W element loaded once per block, reused 8x.
// ---------------------------------------------------------------------------
__global__ __launch_bounds__(768) void qkv_kernel(
    const float* __restrict__ x,
    const float* __restrict__ Wq,
    const float* __restrict__ Wk,
    const float* __restrict__ Wv,
    float* __restrict__ qkv) {
  __shared__ float xs[TS][DD];
  const int tilesPerProj = BB * (SS / TS);
  int bid  = blockIdx.x;
  int proj = bid / tilesPerProj;
  int rem  = bid % tilesPerProj;
  int b    = rem / (SS / TS);
  int s0   = (rem % (SS / TS)) * TS;
  int tid  = threadIdx.x;

  #pragma unroll
  for (int i = 0; i < TS; ++i)
    xs[i][tid] = x[((size_t)(b * SS + s0 + i)) * DD + tid];
  __syncthreads();

  int h = tid >> 6, k = tid & 63;
  const float* W =
      (proj == 0 ? Wq : (proj == 1 ? Wk : Wv)) + (size_t)h * DD * KK + k;

  float acc[TS];
  #pragma unroll
  for (int i = 0; i < TS; ++i) acc[i] = 0.f;

  for (int d = 0; d < DD; ++d) {
    float w = W[(size_t)d * KK];
    #pragma unroll
    for (int i = 0; i < TS; ++i) acc[i] = fmaf(xs[i][d], w, acc[i]);
  }

  float* out = qkv + (size_t)proj * BB * HH * SS * KK +
               ((size_t)(b * HH + h) * SS + s0) * KK + k;
  #pragma unroll
  for (int i = 0; i < TS; ++i) out[(size_t)i * KK] = acc[i];
}

// ---------------------------------------------------------------------------
// Causal attention, online softmax. One wave (64 lanes) per query row;
// lane = k dim. 4 waves/block handle 4 consecutive rows of same (b,h)
// so K/V tiles stay hot in L2.
// ---------------------------------------------------------------------------
__global__ __launch_bounds__(256) void attn_kernel(
    const float* __restrict__ qkv, float* __restrict__ out) {
  const size_t per = (size_t)BB * HH * SS * KK;
  const float* Q  = qkv;
  const float* Kp = qkv + per;
  const float* Vp = qkv + 2 * per;

  int wid = threadIdx.x >> 6, lane = threadIdx.x & 63;
  int gid = blockIdx.x * 4 + wid;
  int b   = gid / (HH * SS);
  int rem = gid % (HH * SS);
  int h   = rem / SS;
  int s   = rem % SS;

  size_t base = ((size_t)(b * HH + h) * SS) * KK;
  float q = Q[base + (size_t)s * KK + lane] * 0.125f;  // 1/sqrt(64)

  float m = -INFINITY, l = 0.f, acc = 0.f;
  for (int t = 0; t <= s; ++t) {
    float kv = Kp[base + (size_t)t * KK + lane];
    float v  = Vp[base + (size_t)t * KK + lane];
    float sc = q * kv;
    #pragma unroll
    for (int off = 32; off; off >>= 1) sc += __shfl_xor(sc, off, 64);
    float nm   = fmaxf(m, sc);
    float corr = __expf(m - nm);
    float p    = __expf(sc - nm);
    l   = l * corr + p;
    acc = acc * corr + p * v;
    m   = nm;
  }
  out[((size_t)(b * SS + s)) * (HH * KK) + h * KK + lane] = acc / l;
}

// ---------------------------------------------------------------------------
extern "C" void kernel_launch(void* const* d_in, const int* in_sizes, int n_in,
                              void* d_out, int out_size, void* d_ws,
                              size_t ws_size, hipStream_t stream) {
  const float* x  = (const float*)d_in[0];
  const float* Wq = (const float*)d_in[1];
  const float* Wk = (const float*)d_in[2];
  const float* Wv = (const float*)d_in[3];
  float* ws  = (float*)d_ws;
  float* o   = (float*)d_out;

  qkv_kernel<<<3 * BB * (SS / TS), 768, 0, stream>>>(x, Wq, Wk, Wv, ws);
  attn_kernel<<<BB * HH * SS / 4, 256, 0, stream>>>(ws, o);
}

// Round 2
// 812.097 us; speedup vs baseline: 9.0636x; 9.0636x over previous
//
#include <hip/hip_runtime.h>
#include <math.h>

#define BB 4
#define SS 2048
#define DD 768
#define HH 12
#define KK 64
#define TS 8

typedef __attribute__((ext_vector_type(8))) short bf16x8;
typedef __attribute__((ext_vector_type(4))) short bf16x4;
typedef __attribute__((ext_vector_type(4))) float f32x4;

static __device__ __forceinline__ short f2bf(float f) {
  union { float f; unsigned u; } v;
  v.f = f;
  unsigned r = (v.u + 0x7fff + ((v.u >> 16) & 1)) >> 16;  // RNE
  return (short)r;
}

// ---------------------------------------------------------------------------
// QKV projection -> bf16. qkv[proj][b][h][s][k], Q pre-scaled by 1/sqrt(64).
// One block per (proj, b, 8-row s-tile). 768 threads = (h,k) pairs.
// ---------------------------------------------------------------------------
__global__ __launch_bounds__(768) void qkv_kernel(
    const float* __restrict__ x,
    const float* __restrict__ Wq,
    const float* __restrict__ Wk,
    const float* __restrict__ Wv,
    short* __restrict__ qkv) {
  __shared__ float xs[TS][DD];
  const int tilesPerProj = BB * (SS / TS);
  int bid  = blockIdx.x;
  int proj = bid / tilesPerProj;
  int rem  = bid % tilesPerProj;
  int b    = rem / (SS / TS);
  int s0   = (rem % (SS / TS)) * TS;
  int tid  = threadIdx.x;

  #pragma unroll
  for (int i = 0; i < TS; ++i)
    xs[i][tid] = x[((size_t)(b * SS + s0 + i)) * DD + tid];
  __syncthreads();

  int h = tid >> 6, k = tid & 63;
  const float* W =
      (proj == 0 ? Wq : (proj == 1 ? Wk : Wv)) + (size_t)h * DD * KK + k;

  float acc[TS];
  #pragma unroll
  for (int i = 0; i < TS; ++i) acc[i] = 0.f;

  for (int d = 0; d < DD; ++d) {
    float w = W[(size_t)d * KK];
    #pragma unroll
    for (int i = 0; i < TS; ++i) acc[i] = fmaf(xs[i][d], w, acc[i]);
  }

  float scale = (proj == 0) ? 0.125f : 1.0f;  // 1/sqrt(64) folded into Q
  short* out = qkv + (size_t)proj * BB * HH * SS * KK +
               ((size_t)(b * HH + h) * SS + s0) * KK + k;
  #pragma unroll
  for (int i = 0; i < TS; ++i) out[(size_t)i * KK] = f2bf(acc[i] * scale);
}

// ---------------------------------------------------------------------------
// Flash attention, MFMA bf16. One wave per 16-row Q-tile.
// QK^T swapped (mfma(K,Q)) so scores for query i live in lanes with
// lane&15==i; that C-layout IS the B-operand layout of 16x16x16 MFMA, so
// P feeds PV directly. PV computed as O^T = V^T * P^T (per-i state aligned).
// ---------------------------------------------------------------------------
__global__ __launch_bounds__(256) void attn_kernel(
    const short* __restrict__ qkv, float* __restrict__ out) {
  const size_t per = (size_t)BB * HH * SS * KK;
  int wid = threadIdx.x >> 6, lane = threadIdx.x & 63;
  int gid = blockIdx.x * 4 + wid;       // Q-tile id, 48 bh * 128 tiles
  int bh  = gid >> 7;
  int qt  = gid & 127;
  int b   = bh / HH, h = bh % HH;
  int s0  = qt * 16;
  int li  = lane & 15, lg = lane >> 4;
  int iglob = s0 + li;

  const short* Qb = qkv + (size_t)bh * SS * KK;
  const short* Kb = qkv + per + (size_t)bh * SS * KK;
  const short* Vb = qkv + 2 * per + (size_t)bh * SS * KK;

  // Q fragment (B-operand): lane holds Q[s0+li][lg*8+j], two k-halves.
  bf16x8 qf0 = *(const bf16x8*)(Qb + (size_t)(s0 + li) * KK + lg * 8);
  bf16x8 qf1 = *(const bf16x8*)(Qb + (size_t)(s0 + li) * KK + lg * 8 + 32);

  f32x4 acc0 = {0.f, 0.f, 0.f, 0.f};
  f32x4 acc1 = acc0, acc2 = acc0, acc3 = acc0;
  float m = -INFINITY, lsum = 0.f;

  for (int t0 = 0; t0 <= s0; t0 += 16) {
    // K fragment (A-operand): lane holds K[t0+li][lg*8+j], two k-halves.
    const short* Krow = Kb + (size_t)(t0 + li) * KK + lg * 8;
    bf16x8 kf0 = *(const bf16x8*)(Krow);
    bf16x8 kf1 = *(const bf16x8*)(Krow + 32);

    f32x4 sc = {0.f, 0.f, 0.f, 0.f};
    sc = __builtin_amdgcn_mfma_f32_16x16x32_bf16(kf0, qf0, sc, 0, 0, 0);
    sc = __builtin_amdgcn_mfma_f32_16x16x32_bf16(kf1, qf1, sc, 0, 0, 0);
    // lane holds S^T: query i = li, key t = t0 + lg*4 + r

    int tbase = t0 + lg * 4;
    #pragma unroll
    for (int r = 0; r < 4; ++r)
      if (tbase + r > iglob) sc[r] = -INFINITY;

    float tm = fmaxf(fmaxf(sc[0], sc[1]), fmaxf(sc[2], sc[3]));
    tm = fmaxf(tm, __shfl_xor(tm, 16, 64));
    tm = fmaxf(tm, __shfl_xor(tm, 32, 64));
    float nm = fmaxf(m, tm);
    float corr = __expf(m - nm);
    m = nm;

    float p0 = __expf(sc[0] - nm), p1 = __expf(sc[1] - nm);
    float p2 = __expf(sc[2] - nm), p3 = __expf(sc[3] - nm);
    float ps = p0 + p1 + p2 + p3;
    ps += __shfl_xor(ps, 16, 64);
    ps += __shfl_xor(ps, 32, 64);
    lsum = lsum * corr + ps;

    #pragma unroll
    for (int r = 0; r < 4; ++r) {
      acc0[r] *= corr; acc1[r] *= corr; acc2[r] *= corr; acc3[r] *= corr;
    }

    bf16x4 pf = {f2bf(p0), f2bf(p1), f2bf(p2), f2bf(p3)};

    // V fragment (A-operand of O^T = V^T P^T):
    // lane holds V[t0+lg*4+j][kk*16+li]
    const short* Vcol = Vb + (size_t)(t0 + lg * 4) * KK + li;
    {
      bf16x4 vf = {Vcol[0], Vcol[KK], Vcol[2 * KK], Vcol[3 * KK]};
      acc0 = __builtin_amdgcn_mfma_f32_16x16x16bf16_1k(vf, pf, acc0, 0, 0, 0);
    }
    {
      const short* Vc = Vcol + 16;
      bf16x4 vf = {Vc[0], Vc[KK], Vc[2 * KK], Vc[3 * KK]};
      acc1 = __builtin_amdgcn_mfma_f32_16x16x16bf16_1k(vf, pf, acc1, 0, 0, 0);
    }
    {
      const short* Vc = Vcol + 32;
      bf16x4 vf = {Vc[0], Vc[KK], Vc[2 * KK], Vc[3 * KK]};
      acc2 = __builtin_amdgcn_mfma_f32_16x16x16bf16_1k(vf, pf, acc2, 0, 0, 0);
    }
    {
      const short* Vc = Vcol + 48;
      bf16x4 vf = {Vc[0], Vc[KK], Vc[2 * KK], Vc[3 * KK]};
      acc3 = __builtin_amdgcn_mfma_f32_16x16x16bf16_1k(vf, pf, acc3, 0, 0, 0);
    }
  }

  // Output: lane holds O[i=li][kd = kk*16 + lg*4 + r]
  float inv = 1.0f / lsum;
  float* orow = out + ((size_t)(b * SS + s0 + li)) * (HH * KK) + h * KK;
  #pragma unroll
  for (int r = 0; r < 4; ++r) {
    orow[lg * 4 + r]      = acc0[r] * inv;
    orow[16 + lg * 4 + r] = acc1[r] * inv;
    orow[32 + lg * 4 + r] = acc2[r] * inv;
    orow[48 + lg * 4 + r] = acc3[r] * inv;
  }
}

// ---------------------------------------------------------------------------
extern "C" void kernel_launch(void* const* d_in, const int* in_sizes, int n_in,
                              void* d_out, int out_size, void* d_ws,
                              size_t ws_size, hipStream_t stream) {
  const float* x  = (const float*)d_in[0];
  const float* Wq = (const float*)d_in[1];
  const float* Wk = (const float*)d_in[2];
  const float* Wv = (const float*)d_in[3];
  short* ws = (short*)d_ws;
  float* o  = (float*)d_out;

  qkv_kernel<<<3 * BB * (SS / TS), 768, 0, stream>>>(x, Wq, Wk, Wv, ws);
  attn_kernel<<<BB * HH * SS / 16 / 4, 256, 0, stream>>>(ws, o);
}

// Round 3
// 346.057 us; speedup vs baseline: 21.2697x; 2.3467x over previous
//
#include <hip/hip_runtime.h>
#include <math.h>

#define BB 4
#define SS 2048
#define DD 768
#define HH 12
#define KK 64

#define NPROJ 3
#define HK    (HH * KK)          // 768
#define NCOLS (NPROJ * HK)       // 2304
#define MROWS (BB * SS)          // 8192
#define PER   (BB * HH * SS * KK)  // 6291456 elements per proj

typedef __attribute__((ext_vector_type(8))) short bf16x8;
typedef __attribute__((ext_vector_type(4))) short bf16x4;
typedef __attribute__((ext_vector_type(4))) float f32x4;

static __device__ __forceinline__ short f2bf(float f) {
  union { float f; unsigned u; } v;
  v.f = f;
  unsigned r = (v.u + 0x7fff + ((v.u >> 16) & 1)) >> 16;  // RNE
  return (short)r;
}

// ---------------------------------------------------------------------------
// x (fp32) -> bf16, flat copy. 4 elems/thread.
// ---------------------------------------------------------------------------
__global__ __launch_bounds__(256) void conv_x(const float* __restrict__ x,
                                              short* __restrict__ xbf) {
  int i = (blockIdx.x * 256 + threadIdx.x) * 4;
  float4 v = *(const float4*)(x + i);
  bf16x4 o = {f2bf(v.x), f2bf(v.y), f2bf(v.z), f2bf(v.w)};
  *(bf16x4*)(xbf + i) = o;
}

// ---------------------------------------------------------------------------
// W (3 x [H][D][K] fp32) -> bf16 transposed wT[n][d], n = proj*768 + h*64 + k.
// Q-scale 1/sqrt(64) folded into proj 0.
// ---------------------------------------------------------------------------
__global__ __launch_bounds__(256) void conv_w(const float* __restrict__ Wq,
                                              const float* __restrict__ Wk,
                                              const float* __restrict__ Wv,
                                              short* __restrict__ wbf) {
  int o = blockIdx.x * 256 + threadIdx.x;  // 2304*768 total
  int n = o / DD, d = o % DD;
  int proj = n / HK;
  int hk = n % HK;
  int h = hk >> 6, k = hk & 63;
  const float* W = proj == 0 ? Wq : (proj == 1 ? Wk : Wv);
  float v = W[(size_t)h * DD * KK + (size_t)d * KK + k];
  if (proj == 0) v *= 0.125f;
  wbf[o] = f2bf(v);
}

// ---------------------------------------------------------------------------
// QKV GEMM: C[m][n] = sum_d xbf[m][d] * wT[n][d].  M=8192, N=2304, K=768.
// m97 structure: 128x128 tile, 4 waves (2x2), 4x4 16x16x32 frags per wave,
// BK=64, global_load_lds width 16. Epilogue scatters bf16 into qkv layout.
// ---------------------------------------------------------------------------
__global__ __launch_bounds__(256) void qkv_gemm(const short* __restrict__ xbf,
                                                const short* __restrict__ wbf,
                                                short* __restrict__ qkv) {
  __shared__ short As[128 * 64];
  __shared__ short Bs[128 * 64];
  int bm = blockIdx.x & 63, bn = blockIdx.x >> 6;
  int m0 = bm * 128, n0 = bn * 128;
  int tid = threadIdx.x, lane = tid & 63, wid = tid >> 6;
  int li = lane & 15, lg = lane >> 4;
  int wm = wid >> 1, wn = wid & 1;

  f32x4 acc[4][4];
  #pragma unroll
  for (int mi = 0; mi < 4; ++mi)
    #pragma unroll
    for (int ni = 0; ni < 4; ++ni)
      acc[mi][ni] = (f32x4){0.f, 0.f, 0.f, 0.f};

  int rowoff = lane >> 3;          // lane/8: row within 8-row chunk
  int kp = (lane & 7) * 8;         // 8-elem (16 B) slice within 64-k row

  for (int kt = 0; kt < DD / 64; ++kt) {
    // ---- stage A and B tiles (each wave: 4 x 1KB issues per tile) ----
    #pragma unroll
    for (int j = 0; j < 4; ++j) {
      int eb = wid * 2048 + j * 512;       // element base (wave-uniform)
      int row = (eb >> 6) + rowoff;        // tile row this lane feeds
      __builtin_amdgcn_global_load_lds(
          (const __attribute__((address_space(1))) void*)(
              xbf + (size_t)(m0 + row) * DD + kt * 64 + kp),
          (__attribute__((address_space(3))) void*)(As + eb), 16, 0, 0);
      __builtin_amdgcn_global_load_lds(
          (const __attribute__((address_space(1))) void*)(
              wbf + (size_t)(n0 + row) * DD + kt * 64 + kp),
          (__attribute__((address_space(3))) void*)(Bs + eb), 16, 0, 0);
    }
    __syncthreads();

    // ---- compute: 2 k-substeps x 4x4 frags ----
    #pragma unroll
    for (int kk = 0; kk < 2; ++kk) {
      bf16x8 af[4], bfr[4];
      #pragma unroll
      for (int mi = 0; mi < 4; ++mi)
        af[mi] = *(const bf16x8*)(As + (wm * 64 + mi * 16 + li) * 64 +
                                  kk * 32 + lg * 8);
      #pragma unroll
      for (int ni = 0; ni < 4; ++ni)
        bfr[ni] = *(const bf16x8*)(Bs + (wn * 64 + ni * 16 + li) * 64 +
                                   kk * 32 + lg * 8);
      #pragma unroll
      for (int mi = 0; mi < 4; ++mi)
        #pragma unroll
        for (int ni = 0; ni < 4; ++ni)
          acc[mi][ni] = __builtin_amdgcn_mfma_f32_16x16x32_bf16(
              af[mi], bfr[ni], acc[mi][ni], 0, 0, 0);
    }
    __syncthreads();
  }

  // ---- epilogue: C layout col=lane&15, row=(lane>>4)*4+r ----
  int proj = n0 / HK;  // 768 % 128 == 0 -> uniform per block
  #pragma unroll
  for (int ni = 0; ni < 4; ++ni) {
    int ncol = n0 + wn * 64 + ni * 16 + li;
    int hk = ncol % HK;
    int h = hk >> 6, k = hk & 63;
    #pragma unroll
    for (int mi = 0; mi < 4; ++mi) {
      #pragma unroll
      for (int r = 0; r < 4; ++r) {
        int mrow = m0 + wm * 64 + mi * 16 + lg * 4 + r;
        int b = mrow >> 11, s = mrow & 2047;
        qkv[(size_t)proj * PER + ((size_t)(b * HH + h) * SS + s) * KK + k] =
            f2bf(acc[mi][ni][r]);
      }
    }
  }
}

// ---------------------------------------------------------------------------
// Flash attention, MFMA bf16 (unchanged from round 2).
// ---------------------------------------------------------------------------
__global__ __launch_bounds__(256) void attn_kernel(
    const short* __restrict__ qkv, float* __restrict__ out) {
  const size_t per = (size_t)PER;
  int wid = threadIdx.x >> 6, lane = threadIdx.x & 63;
  int gid = blockIdx.x * 4 + wid;
  int bh  = gid >> 7;
  int qt  = gid & 127;
  int b   = bh / HH, h = bh % HH;
  int s0  = qt * 16;
  int li  = lane & 15, lg = lane >> 4;
  int iglob = s0 + li;

  const short* Qb = qkv + (size_t)bh * SS * KK;
  const short* Kb = qkv + per + (size_t)bh * SS * KK;
  const short* Vb = qkv + 2 * per + (size_t)bh * SS * KK;

  bf16x8 qf0 = *(const bf16x8*)(Qb + (size_t)(s0 + li) * KK + lg * 8);
  bf16x8 qf1 = *(const bf16x8*)(Qb + (size_t)(s0 + li) * KK + lg * 8 + 32);

  f32x4 acc0 = {0.f, 0.f, 0.f, 0.f};
  f32x4 acc1 = acc0, acc2 = acc0, acc3 = acc0;
  float m = -INFINITY, lsum = 0.f;

  for (int t0 = 0; t0 <= s0; t0 += 16) {
    const short* Krow = Kb + (size_t)(t0 + li) * KK + lg * 8;
    bf16x8 kf0 = *(const bf16x8*)(Krow);
    bf16x8 kf1 = *(const bf16x8*)(Krow + 32);

    f32x4 sc = {0.f, 0.f, 0.f, 0.f};
    sc = __builtin_amdgcn_mfma_f32_16x16x32_bf16(kf0, qf0, sc, 0, 0, 0);
    sc = __builtin_amdgcn_mfma_f32_16x16x32_bf16(kf1, qf1, sc, 0, 0, 0);

    int tbase = t0 + lg * 4;
    #pragma unroll
    for (int r = 0; r < 4; ++r)
      if (tbase + r > iglob) sc[r] = -INFINITY;

    float tm = fmaxf(fmaxf(sc[0], sc[1]), fmaxf(sc[2], sc[3]));
    tm = fmaxf(tm, __shfl_xor(tm, 16, 64));
    tm = fmaxf(tm, __shfl_xor(tm, 32, 64));
    float nm = fmaxf(m, tm);
    float corr = __expf(m - nm);
    m = nm;

    float p0 = __expf(sc[0] - nm), p1 = __expf(sc[1] - nm);
    float p2 = __expf(sc[2] - nm), p3 = __expf(sc[3] - nm);
    float ps = p0 + p1 + p2 + p3;
    ps += __shfl_xor(ps, 16, 64);
    ps += __shfl_xor(ps, 32, 64);
    lsum = lsum * corr + ps;

    #pragma unroll
    for (int r = 0; r < 4; ++r) {
      acc0[r] *= corr; acc1[r] *= corr; acc2[r] *= corr; acc3[r] *= corr;
    }

    bf16x4 pf = {f2bf(p0), f2bf(p1), f2bf(p2), f2bf(p3)};

    const short* Vcol = Vb + (size_t)(t0 + lg * 4) * KK + li;
    {
      bf16x4 vf = {Vcol[0], Vcol[KK], Vcol[2 * KK], Vcol[3 * KK]};
      acc0 = __builtin_amdgcn_mfma_f32_16x16x16bf16_1k(vf, pf, acc0, 0, 0, 0);
    }
    {
      const short* Vc = Vcol + 16;
      bf16x4 vf = {Vc[0], Vc[KK], Vc[2 * KK], Vc[3 * KK]};
      acc1 = __builtin_amdgcn_mfma_f32_16x16x16bf16_1k(vf, pf, acc1, 0, 0, 0);
    }
    {
      const short* Vc = Vcol + 32;
      bf16x4 vf = {Vc[0], Vc[KK], Vc[2 * KK], Vc[3 * KK]};
      acc2 = __builtin_amdgcn_mfma_f32_16x16x16bf16_1k(vf, pf, acc2, 0, 0, 0);
    }
    {
      const short* Vc = Vcol + 48;
      bf16x4 vf = {Vc[0], Vc[KK], Vc[2 * KK], Vc[3 * KK]};
      acc3 = __builtin_amdgcn_mfma_f32_16x16x16bf16_1k(vf, pf, acc3, 0, 0, 0);
    }
  }

  float inv = 1.0f / lsum;
  float* orow = out + ((size_t)(b * SS + s0 + li)) * (HH * KK) + h * KK;
  #pragma unroll
  for (int r = 0; r < 4; ++r) {
    orow[lg * 4 + r]      = acc0[r] * inv;
    orow[16 + lg * 4 + r] = acc1[r] * inv;
    orow[32 + lg * 4 + r] = acc2[r] * inv;
    orow[48 + lg * 4 + r] = acc3[r] * inv;
  }
}

// ---------------------------------------------------------------------------
extern "C" void kernel_launch(void* const* d_in, const int* in_sizes, int n_in,
                              void* d_out, int out_size, void* d_ws,
                              size_t ws_size, hipStream_t stream) {
  const float* x  = (const float*)d_in[0];
  const float* Wq = (const float*)d_in[1];
  const float* Wk = (const float*)d_in[2];
  const float* Wv = (const float*)d_in[3];
  short* ws  = (short*)d_ws;
  short* qkv = ws;                       // 3 * PER shorts
  short* xbf = ws + (size_t)3 * PER;     // MROWS*DD shorts
  short* wbf = xbf + (size_t)MROWS * DD; // NCOLS*DD shorts
  float* o   = (float*)d_out;

  conv_x<<<(MROWS * DD) / 4 / 256, 256, 0, stream>>>(x, xbf);
  conv_w<<<(NCOLS * DD) / 256, 256, 0, stream>>>(Wq, Wk, Wv, wbf);
  qkv_gemm<<<(MROWS / 128) * (NCOLS / 128), 256, 0, stream>>>(xbf, wbf, qkv);
  attn_kernel<<<BB * HH * SS / 16 / 4, 256, 0, stream>>>(ws, o);
}

// Round 4
// 337.924 us; speedup vs baseline: 21.7817x; 1.0241x over previous
//
#include <hip/hip_runtime.h>
#include <math.h>

#define BB 4
#define SS 2048
#define DD 768
#define HH 12
#define KK 64

#define NPROJ 3
#define HK    (HH * KK)          // 768
#define NCOLS (NPROJ * HK)       // 2304
#define MROWS (BB * SS)          // 8192
#define PER   (BB * HH * SS * KK)  // 6291456 elements per proj

typedef __attribute__((ext_vector_type(8))) short bf16x8;
typedef __attribute__((ext_vector_type(4))) short bf16x4;
typedef __attribute__((ext_vector_type(4))) float f32x4;

static __device__ __forceinline__ short f2bf(float f) {
  union { float f; unsigned u; } v;
  v.f = f;
  unsigned r = (v.u + 0x7fff + ((v.u >> 16) & 1)) >> 16;  // RNE
  return (short)r;
}

// ---------------------------------------------------------------------------
// x (fp32) -> bf16, flat copy. 4 elems/thread.
// ---------------------------------------------------------------------------
__global__ __launch_bounds__(256) void conv_x(const float* __restrict__ x,
                                              short* __restrict__ xbf) {
  int i = (blockIdx.x * 256 + threadIdx.x) * 4;
  float4 v = *(const float4*)(x + i);
  bf16x4 o = {f2bf(v.x), f2bf(v.y), f2bf(v.z), f2bf(v.w)};
  *(bf16x4*)(xbf + i) = o;
}

// ---------------------------------------------------------------------------
// W (3 x [H][D][K] fp32) -> bf16 transposed wT[n][d], n = proj*768 + h*64 + k.
// Q-scale 1/sqrt(64) folded into proj 0.
// ---------------------------------------------------------------------------
__global__ __launch_bounds__(256) void conv_w(const float* __restrict__ Wq,
                                              const float* __restrict__ Wk,
                                              const float* __restrict__ Wv,
                                              short* __restrict__ wbf) {
  int o = blockIdx.x * 256 + threadIdx.x;  // 2304*768 total
  int n = o / DD, d = o % DD;
  int proj = n / HK;
  int hk = n % HK;
  int h = hk >> 6, k = hk & 63;
  const float* W = proj == 0 ? Wq : (proj == 1 ? Wk : Wv);
  float v = W[(size_t)h * DD * KK + (size_t)d * KK + k];
  if (proj == 0) v *= 0.125f;
  wbf[o] = f2bf(v);
}

// ---------------------------------------------------------------------------
// QKV GEMM: C[m][n] = sum_d xbf[m][d] * wT[n][d].  M=8192, N=2304, K=768.
// m97 structure: 128x128 tile, 4 waves (2x2), 4x4 16x16x32 frags per wave,
// BK=64, global_load_lds width 16. Epilogue scatters bf16 into qkv layout;
// V (proj 2) is written TRANSPOSED: Vt[bh][k][s] for vectorized attn loads.
// ---------------------------------------------------------------------------
__global__ __launch_bounds__(256) void qkv_gemm(const short* __restrict__ xbf,
                                                const short* __restrict__ wbf,
                                                short* __restrict__ qkv) {
  __shared__ short As[128 * 64];
  __shared__ short Bs[128 * 64];
  int bm = blockIdx.x & 63, bn = blockIdx.x >> 6;
  int m0 = bm * 128, n0 = bn * 128;
  int tid = threadIdx.x, lane = tid & 63, wid = tid >> 6;
  int li = lane & 15, lg = lane >> 4;
  int wm = wid >> 1, wn = wid & 1;

  f32x4 acc[4][4];
  #pragma unroll
  for (int mi = 0; mi < 4; ++mi)
    #pragma unroll
    for (int ni = 0; ni < 4; ++ni)
      acc[mi][ni] = (f32x4){0.f, 0.f, 0.f, 0.f};

  int rowoff = lane >> 3;          // lane/8: row within 8-row chunk
  int kp = (lane & 7) * 8;         // 8-elem (16 B) slice within 64-k row

  for (int kt = 0; kt < DD / 64; ++kt) {
    #pragma unroll
    for (int j = 0; j < 4; ++j) {
      int eb = wid * 2048 + j * 512;       // element base (wave-uniform)
      int row = (eb >> 6) + rowoff;        // tile row this lane feeds
      __builtin_amdgcn_global_load_lds(
          (const __attribute__((address_space(1))) void*)(
              xbf + (size_t)(m0 + row) * DD + kt * 64 + kp),
          (__attribute__((address_space(3))) void*)(As + eb), 16, 0, 0);
      __builtin_amdgcn_global_load_lds(
          (const __attribute__((address_space(1))) void*)(
              wbf + (size_t)(n0 + row) * DD + kt * 64 + kp),
          (__attribute__((address_space(3))) void*)(Bs + eb), 16, 0, 0);
    }
    __syncthreads();

    #pragma unroll
    for (int kk = 0; kk < 2; ++kk) {
      bf16x8 af[4], bfr[4];
      #pragma unroll
      for (int mi = 0; mi < 4; ++mi)
        af[mi] = *(const bf16x8*)(As + (wm * 64 + mi * 16 + li) * 64 +
                                  kk * 32 + lg * 8);
      #pragma unroll
      for (int ni = 0; ni < 4; ++ni)
        bfr[ni] = *(const bf16x8*)(Bs + (wn * 64 + ni * 16 + li) * 64 +
                                   kk * 32 + lg * 8);
      #pragma unroll
      for (int mi = 0; mi < 4; ++mi)
        #pragma unroll
        for (int ni = 0; ni < 4; ++ni)
          acc[mi][ni] = __builtin_amdgcn_mfma_f32_16x16x32_bf16(
              af[mi], bfr[ni], acc[mi][ni], 0, 0, 0);
    }
    __syncthreads();
  }

  // ---- epilogue: C layout col=lane&15, row=(lane>>4)*4+r ----
  int proj = n0 / HK;  // 768 % 128 == 0 -> uniform per block
  #pragma unroll
  for (int ni = 0; ni < 4; ++ni) {
    int ncol = n0 + wn * 64 + ni * 16 + li;
    int hk = ncol % HK;
    int h = hk >> 6, k = hk & 63;
    #pragma unroll
    for (int mi = 0; mi < 4; ++mi) {
      int mrow0 = m0 + wm * 64 + mi * 16 + lg * 4;
      int b = mrow0 >> 11, s = mrow0 & 2047;  // 4 consecutive s, same b
      if (proj == 2) {
        // Vt[bh][k][s]: contiguous in r -> 8B vector store
        bf16x4 o = {f2bf(acc[mi][ni][0]), f2bf(acc[mi][ni][1]),
                    f2bf(acc[mi][ni][2]), f2bf(acc[mi][ni][3])};
        *(bf16x4*)(qkv + 2 * (size_t)PER +
                   ((size_t)(b * HH + h) * KK + k) * SS + s) = o;
      } else {
        #pragma unroll
        for (int r = 0; r < 4; ++r)
          qkv[(size_t)proj * PER +
              ((size_t)(b * HH + h) * SS + s + r) * KK + k] =
              f2bf(acc[mi][ni][r]);
      }
    }
  }
}

// ---------------------------------------------------------------------------
// One 16-row tile's flash step: QK^T (swapped), mask, online softmax, PV.
// ---------------------------------------------------------------------------
static __device__ __forceinline__ void tile_step(
    bf16x8 kf0, bf16x8 kf1, bf16x8 qf0, bf16x8 qf1, const bf16x4* vf,
    int tbase, int iglob, float& m, float& lsum, f32x4* acc) {
  f32x4 sc = {0.f, 0.f, 0.f, 0.f};
  sc = __builtin_amdgcn_mfma_f32_16x16x32_bf16(kf0, qf0, sc, 0, 0, 0);
  sc = __builtin_amdgcn_mfma_f32_16x16x32_bf16(kf1, qf1, sc, 0, 0, 0);
  #pragma unroll
  for (int r = 0; r < 4; ++r)
    if (tbase + r > iglob) sc[r] = -INFINITY;

  float tm = fmaxf(fmaxf(sc[0], sc[1]), fmaxf(sc[2], sc[3]));
  tm = fmaxf(tm, __shfl_xor(tm, 16, 64));
  tm = fmaxf(tm, __shfl_xor(tm, 32, 64));
  float nm = fmaxf(m, tm);
  float corr = __expf(m - nm);
  m = nm;

  float p0 = __expf(sc[0] - nm), p1 = __expf(sc[1] - nm);
  float p2 = __expf(sc[2] - nm), p3 = __expf(sc[3] - nm);
  float ps = p0 + p1 + p2 + p3;
  ps += __shfl_xor(ps, 16, 64);
  ps += __shfl_xor(ps, 32, 64);
  lsum = lsum * corr + ps;

  bf16x4 pf = {f2bf(p0), f2bf(p1), f2bf(p2), f2bf(p3)};
  #pragma unroll
  for (int kk = 0; kk < 4; ++kk) {
    #pragma unroll
    for (int r = 0; r < 4; ++r) acc[kk][r] *= corr;
    acc[kk] =
        __builtin_amdgcn_mfma_f32_16x16x16bf16_1k(vf[kk], pf, acc[kk], 0, 0, 0);
  }
}

// ---------------------------------------------------------------------------
// Flash attention: one wave per 32 queries (two 16-row tiles A,B sharing the
// k-loop -> K/V fragment loads amortized 2x). V read from transposed Vt
// (bf16x4 vector loads). Heaviest q-groups dispatched first (reversed order).
// ---------------------------------------------------------------------------
__global__ __launch_bounds__(256) void attn_kernel(
    const short* __restrict__ qkv, float* __restrict__ out) {
  int wid = threadIdx.x >> 6, lane = threadIdx.x & 63;
  int gid = blockIdx.x * 4 + wid;  // 48 bh * 64 qgroups
  int bh  = gid >> 6;
  int qg  = 63 - (gid & 63);       // reversed: heavy first
  int b   = bh / HH, h = bh % HH;
  int s0a = qg * 32, s0b = s0a + 16;
  int li  = lane & 15, lg = lane >> 4;
  int iA = s0a + li, iB = s0b + li;

  const short* Qb = qkv + (size_t)bh * SS * KK;
  const short* Kb = qkv + (size_t)PER + (size_t)bh * SS * KK;
  const short* Vt = qkv + 2 * (size_t)PER + (size_t)bh * KK * SS;

  bf16x8 qa0 = *(const bf16x8*)(Qb + (size_t)(s0a + li) * KK + lg * 8);
  bf16x8 qa1 = *(const bf16x8*)(Qb + (size_t)(s0a + li) * KK + lg * 8 + 32);
  bf16x8 qb0 = *(const bf16x8*)(Qb + (size_t)(s0b + li) * KK + lg * 8);
  bf16x8 qb1 = *(const bf16x8*)(Qb + (size_t)(s0b + li) * KK + lg * 8 + 32);

  f32x4 accA[4], accB[4];
  #pragma unroll
  for (int kk = 0; kk < 4; ++kk) {
    accA[kk] = (f32x4){0.f, 0.f, 0.f, 0.f};
    accB[kk] = (f32x4){0.f, 0.f, 0.f, 0.f};
  }
  float mA = -INFINITY, lA = 0.f, mB = -INFINITY, lB = 0.f;

  for (int t0 = 0; t0 <= s0b; t0 += 16) {
    const short* Krow = Kb + (size_t)(t0 + li) * KK + lg * 8;
    bf16x8 kf0 = *(const bf16x8*)(Krow);
    bf16x8 kf1 = *(const bf16x8*)(Krow + 32);

    bf16x4 vf[4];
    #pragma unroll
    for (int kk = 0; kk < 4; ++kk)
      vf[kk] = *(const bf16x4*)(Vt + (size_t)(kk * 16 + li) * SS + t0 + lg * 4);

    int tbase = t0 + lg * 4;
    tile_step(kf0, kf1, qb0, qb1, vf, tbase, iB, mB, lB, accB);
    if (t0 <= s0a)
      tile_step(kf0, kf1, qa0, qa1, vf, tbase, iA, mA, lA, accA);
  }

  float invA = 1.0f / lA, invB = 1.0f / lB;
  float* orowA = out + ((size_t)(b * SS + s0a + li)) * HK + h * KK;
  float* orowB = out + ((size_t)(b * SS + s0b + li)) * HK + h * KK;
  #pragma unroll
  for (int kk = 0; kk < 4; ++kk) {
    #pragma unroll
    for (int r = 0; r < 4; ++r) {
      orowA[kk * 16 + lg * 4 + r] = accA[kk][r] * invA;
      orowB[kk * 16 + lg * 4 + r] = accB[kk][r] * invB;
    }
  }
}

// ---------------------------------------------------------------------------
extern "C" void kernel_launch(void* const* d_in, const int* in_sizes, int n_in,
                              void* d_out, int out_size, void* d_ws,
                              size_t ws_size, hipStream_t stream) {
  const float* x  = (const float*)d_in[0];
  const float* Wq = (const float*)d_in[1];
  const float* Wk = (const float*)d_in[2];
  const float* Wv = (const float*)d_in[3];
  short* ws  = (short*)d_ws;
  short* qkv = ws;                       // 3 * PER shorts
  short* xbf = ws + (size_t)3 * PER;     // MROWS*DD shorts
  short* wbf = xbf + (size_t)MROWS * DD; // NCOLS*DD shorts
  float* o   = (float*)d_out;

  conv_x<<<(MROWS * DD) / 4 / 256, 256, 0, stream>>>(x, xbf);
  conv_w<<<(NCOLS * DD) / 256, 256, 0, stream>>>(Wq, Wk, Wv, wbf);
  qkv_gemm<<<(MROWS / 128) * (NCOLS / 128), 256, 0, stream>>>(xbf, wbf, qkv);
  attn_kernel<<<BB * HH * (SS / 32) / 4, 256, 0, stream>>>(ws, o);
}

// Round 5
// 229.505 us; speedup vs baseline: 32.0715x; 1.4724x over previous
//
#include <hip/hip_runtime.h>
#include <math.h>

#define BB 4
#define SS 2048
#define DD 768
#define HH 12
#define KK 64

#define NPROJ 3
#define HK    (HH * KK)          // 768
#define NCOLS (NPROJ * HK)       // 2304
#define MROWS (BB * SS)          // 8192
#define PER   (BB * HH * SS * KK)  // 6291456 elements per proj

typedef __attribute__((ext_vector_type(8))) short bf16x8;
typedef __attribute__((ext_vector_type(4))) short bf16x4;
typedef __attribute__((ext_vector_type(4))) float f32x4;

static __device__ __forceinline__ short f2bf(float f) {
  union { float f; unsigned u; } v;
  v.f = f;
  unsigned r = (v.u + 0x7fff + ((v.u >> 16) & 1)) >> 16;  // RNE
  return (short)r;
}

// ---------------------------------------------------------------------------
// x (fp32) -> bf16, flat copy. 4 elems/thread.
// ---------------------------------------------------------------------------
__global__ __launch_bounds__(256) void conv_x(const float* __restrict__ x,
                                              short* __restrict__ xbf) {
  int i = (blockIdx.x * 256 + threadIdx.x) * 4;
  float4 v = *(const float4*)(x + i);
  bf16x4 o = {f2bf(v.x), f2bf(v.y), f2bf(v.z), f2bf(v.w)};
  *(bf16x4*)(xbf + i) = o;
}

// ---------------------------------------------------------------------------
// W (3 x [H][D][K] fp32) -> bf16 transposed wT[n][d], n = proj*768 + h*64 + k.
// Q-scale 1/sqrt(64) folded into proj 0.
// ---------------------------------------------------------------------------
__global__ __launch_bounds__(256) void conv_w(const float* __restrict__ Wq,
                                              const float* __restrict__ Wk,
                                              const float* __restrict__ Wv,
                                              short* __restrict__ wbf) {
  int o = blockIdx.x * 256 + threadIdx.x;  // 2304*768 total
  int n = o / DD, d = o % DD;
  int proj = n / HK;
  int hk = n % HK;
  int h = hk >> 6, k = hk & 63;
  const float* W = proj == 0 ? Wq : (proj == 1 ? Wk : Wv);
  float v = W[(size_t)h * DD * KK + (size_t)d * KK + k];
  if (proj == 0) v *= 0.125f;
  wbf[o] = f2bf(v);
}

// ---------------------------------------------------------------------------
// QKV GEMM (unchanged from R3): C[m][n] = sum_d xbf[m][d] * wT[n][d].
// V (proj 2) written TRANSPOSED: Vt[bh][k][s].
// ---------------------------------------------------------------------------
__global__ __launch_bounds__(256) void qkv_gemm(const short* __restrict__ xbf,
                                                const short* __restrict__ wbf,
                                                short* __restrict__ qkv) {
  __shared__ short As[128 * 64];
  __shared__ short Bs[128 * 64];
  int bm = blockIdx.x & 63, bn = blockIdx.x >> 6;
  int m0 = bm * 128, n0 = bn * 128;
  int tid = threadIdx.x, lane = tid & 63, wid = tid >> 6;
  int li = lane & 15, lg = lane >> 4;
  int wm = wid >> 1, wn = wid & 1;

  f32x4 acc[4][4];
  #pragma unroll
  for (int mi = 0; mi < 4; ++mi)
    #pragma unroll
    for (int ni = 0; ni < 4; ++ni)
      acc[mi][ni] = (f32x4){0.f, 0.f, 0.f, 0.f};

  int rowoff = lane >> 3;
  int kp = (lane & 7) * 8;

  for (int kt = 0; kt < DD / 64; ++kt) {
    #pragma unroll
    for (int j = 0; j < 4; ++j) {
      int eb = wid * 2048 + j * 512;
      int row = (eb >> 6) + rowoff;
      __builtin_amdgcn_global_load_lds(
          (const __attribute__((address_space(1))) void*)(
              xbf + (size_t)(m0 + row) * DD + kt * 64 + kp),
          (__attribute__((address_space(3))) void*)(As + eb), 16, 0, 0);
      __builtin_amdgcn_global_load_lds(
          (const __attribute__((address_space(1))) void*)(
              wbf + (size_t)(n0 + row) * DD + kt * 64 + kp),
          (__attribute__((address_space(3))) void*)(Bs + eb), 16, 0, 0);
    }
    __syncthreads();

    #pragma unroll
    for (int kk = 0; kk < 2; ++kk) {
      bf16x8 af[4], bfr[4];
      #pragma unroll
      for (int mi = 0; mi < 4; ++mi)
        af[mi] = *(const bf16x8*)(As + (wm * 64 + mi * 16 + li) * 64 +
                                  kk * 32 + lg * 8);
      #pragma unroll
      for (int ni = 0; ni < 4; ++ni)
        bfr[ni] = *(const bf16x8*)(Bs + (wn * 64 + ni * 16 + li) * 64 +
                                   kk * 32 + lg * 8);
      #pragma unroll
      for (int mi = 0; mi < 4; ++mi)
        #pragma unroll
        for (int ni = 0; ni < 4; ++ni)
          acc[mi][ni] = __builtin_amdgcn_mfma_f32_16x16x32_bf16(
              af[mi], bfr[ni], acc[mi][ni], 0, 0, 0);
    }
    __syncthreads();
  }

  int proj = n0 / HK;
  #pragma unroll
  for (int ni = 0; ni < 4; ++ni) {
    int ncol = n0 + wn * 64 + ni * 16 + li;
    int hk = ncol % HK;
    int h = hk >> 6, k = hk & 63;
    #pragma unroll
    for (int mi = 0; mi < 4; ++mi) {
      int mrow0 = m0 + wm * 64 + mi * 16 + lg * 4;
      int b = mrow0 >> 11, s = mrow0 & 2047;
      if (proj == 2) {
        bf16x4 o = {f2bf(acc[mi][ni][0]), f2bf(acc[mi][ni][1]),
                    f2bf(acc[mi][ni][2]), f2bf(acc[mi][ni][3])};
        *(bf16x4*)(qkv + 2 * (size_t)PER +
                   ((size_t)(b * HH + h) * KK + k) * SS + s) = o;
      } else {
        #pragma unroll
        for (int r = 0; r < 4; ++r)
          qkv[(size_t)proj * PER +
              ((size_t)(b * HH + h) * SS + s + r) * KK + k] =
              f2bf(acc[mi][ni][r]);
      }
    }
  }
}

// ---------------------------------------------------------------------------
// One 16-row tile's flash step with defer-max (T13, THR=8).
// ---------------------------------------------------------------------------
static __device__ __forceinline__ void tile_step(
    bf16x8 kf0, bf16x8 kf1, bf16x8 qf0, bf16x8 qf1, const bf16x4* vf,
    int tbase, int iglob, float& m, float& lsum, f32x4* acc) {
  f32x4 sc = {0.f, 0.f, 0.f, 0.f};
  sc = __builtin_amdgcn_mfma_f32_16x16x32_bf16(kf0, qf0, sc, 0, 0, 0);
  sc = __builtin_amdgcn_mfma_f32_16x16x32_bf16(kf1, qf1, sc, 0, 0, 0);
  #pragma unroll
  for (int r = 0; r < 4; ++r)
    if (tbase + r > iglob) sc[r] = -INFINITY;

  float tm = fmaxf(fmaxf(sc[0], sc[1]), fmaxf(sc[2], sc[3]));
  tm = fmaxf(tm, __shfl_xor(tm, 16, 64));
  tm = fmaxf(tm, __shfl_xor(tm, 32, 64));
  if (!__all(tm <= m + 8.f)) {  // rescale only when max grows materially
    float nm = fmaxf(m, tm);
    float corr = __expf(m - nm);
    m = nm;
    lsum *= corr;
    #pragma unroll
    for (int kk = 0; kk < 4; ++kk)
      #pragma unroll
      for (int r = 0; r < 4; ++r) acc[kk][r] *= corr;
  }

  float p0 = __expf(sc[0] - m), p1 = __expf(sc[1] - m);
  float p2 = __expf(sc[2] - m), p3 = __expf(sc[3] - m);
  float ps = p0 + p1 + p2 + p3;
  ps += __shfl_xor(ps, 16, 64);
  ps += __shfl_xor(ps, 32, 64);
  lsum += ps;

  bf16x4 pf = {f2bf(p0), f2bf(p1), f2bf(p2), f2bf(p3)};
  #pragma unroll
  for (int kk = 0; kk < 4; ++kk)
    acc[kk] =
        __builtin_amdgcn_mfma_f32_16x16x16bf16_1k(vf[kk], pf, acc[kk], 0, 0, 0);
}

// ---------------------------------------------------------------------------
// Flash attention, intra-block 4-way split-K.
// Block = one 32-query group (tiles A,B). Wave w handles key tiles
// t0 = (w + 4j)*16 with private online-softmax state; partials merged via
// LDS (flash-decode combine). K/V register-prefetched one iter ahead.
// ---------------------------------------------------------------------------
__global__ __launch_bounds__(256) void attn_kernel(
    const short* __restrict__ qkv, float* __restrict__ out) {
  __shared__ float accL[4][2][16][72];
  __shared__ float mlL[4][2][2][16];

  int wid = threadIdx.x >> 6, lane = threadIdx.x & 63;
  int bh = blockIdx.x % 48;          // qg-major, heavy qg first
  int qg = 63 - (blockIdx.x / 48);
  int b = bh / HH, h = bh % HH;
  int s0a = qg * 32, s0b = s0a + 16;
  int li = lane & 15, lg = lane >> 4;
  int iA = s0a + li, iB = s0b + li;

  const short* Qb = qkv + (size_t)bh * SS * KK;
  const short* Kb = qkv + (size_t)PER + (size_t)bh * SS * KK;
  const short* Vt = qkv + 2 * (size_t)PER + (size_t)bh * KK * SS;

  bf16x8 qa0 = *(const bf16x8*)(Qb + (size_t)(s0a + li) * KK + lg * 8);
  bf16x8 qa1 = *(const bf16x8*)(Qb + (size_t)(s0a + li) * KK + lg * 8 + 32);
  bf16x8 qb0 = *(const bf16x8*)(Qb + (size_t)(s0b + li) * KK + lg * 8);
  bf16x8 qb1 = *(const bf16x8*)(Qb + (size_t)(s0b + li) * KK + lg * 8 + 32);

  f32x4 accA[4], accB[4];
  #pragma unroll
  for (int kk = 0; kk < 4; ++kk) {
    accA[kk] = (f32x4){0.f, 0.f, 0.f, 0.f};
    accB[kk] = (f32x4){0.f, 0.f, 0.f, 0.f};
  }
  float mA = -INFINITY, lA = 0.f, mB = -INFINITY, lB = 0.f;

  const int Tend = s0b + 16;  // exclusive key bound
  int t0 = wid * 16;

  bf16x8 kc0, kc1;
  bf16x4 vc[4];
  if (t0 < Tend) {
    const short* Krow = Kb + (size_t)(t0 + li) * KK + lg * 8;
    kc0 = *(const bf16x8*)(Krow);
    kc1 = *(const bf16x8*)(Krow + 32);
    #pragma unroll
    for (int kk = 0; kk < 4; ++kk)
      vc[kk] =
          *(const bf16x4*)(Vt + (size_t)(kk * 16 + li) * SS + t0 + lg * 4);
  }

  for (; t0 < Tend; t0 += 64) {
    // prefetch next (clamped, branchless)
    int tn = t0 + 64 < Tend ? t0 + 64 : t0;
    const short* Krn = Kb + (size_t)(tn + li) * KK + lg * 8;
    bf16x8 kn0 = *(const bf16x8*)(Krn);
    bf16x8 kn1 = *(const bf16x8*)(Krn + 32);
    bf16x4 vn[4];
    #pragma unroll
    for (int kk = 0; kk < 4; ++kk)
      vn[kk] =
          *(const bf16x4*)(Vt + (size_t)(kk * 16 + li) * SS + tn + lg * 4);

    int tbase = t0 + lg * 4;
    tile_step(kc0, kc1, qb0, qb1, vc, tbase, iB, mB, lB, accB);
    if (t0 <= s0a)
      tile_step(kc0, kc1, qa0, qa1, vc, tbase, iA, mA, lA, accA);

    kc0 = kn0; kc1 = kn1;
    #pragma unroll
    for (int kk = 0; kk < 4; ++kk) vc[kk] = vn[kk];
  }

  // ---- write partials ----
  #pragma unroll
  for (int kk = 0; kk < 4; ++kk) {
    *(f32x4*)&accL[wid][0][li][kk * 16 + lg * 4] = accA[kk];
    *(f32x4*)&accL[wid][1][li][kk * 16 + lg * 4] = accB[kk];
  }
  if (lg == 0) {
    mlL[wid][0][0][li] = mA; mlL[wid][0][1][li] = lA;
    mlL[wid][1][0][li] = mB; mlL[wid][1][1][li] = lB;
  }
  __syncthreads();

  // ---- merge: wave 0 -> tile A, wave 1 -> tile B ----
  if (wid < 2) {
    int t = wid;
    float M = -INFINITY;
    #pragma unroll
    for (int w = 0; w < 4; ++w) M = fmaxf(M, mlL[w][t][0][li]);
    float scw[4], L = 0.f;
    #pragma unroll
    for (int w = 0; w < 4; ++w) {
      scw[w] = __expf(mlL[w][t][0][li] - M);
      L += mlL[w][t][1][li] * scw[w];
    }
    float inv = 1.0f / L;
    int s = s0a + t * 16 + li;
    float* orow = out + ((size_t)(b * SS + s)) * HK + h * KK;
    #pragma unroll
    for (int kk = 0; kk < 4; ++kk) {
      f32x4 o = {0.f, 0.f, 0.f, 0.f};
      #pragma unroll
      for (int w = 0; w < 4; ++w) {
        f32x4 a = *(const f32x4*)&accL[w][t][li][kk * 16 + lg * 4];
        #pragma unroll
        for (int r = 0; r < 4; ++r) o[r] += a[r] * scw[w];
      }
      #pragma unroll
      for (int r = 0; r < 4; ++r) o[r] *= inv;
      *(float4*)(orow + kk * 16 + lg * 4) = *(float4*)&o;
    }
  }
}

// ---------------------------------------------------------------------------
extern "C" void kernel_launch(void* const* d_in, const int* in_sizes, int n_in,
                              void* d_out, int out_size, void* d_ws,
                              size_t ws_size, hipStream_t stream) {
  const float* x  = (const float*)d_in[0];
  const float* Wq = (const float*)d_in[1];
  const float* Wk = (const float*)d_in[2];
  const float* Wv = (const float*)d_in[3];
  short* ws  = (short*)d_ws;
  short* qkv = ws;                       // 3 * PER shorts
  short* xbf = ws + (size_t)3 * PER;     // MROWS*DD shorts
  short* wbf = xbf + (size_t)MROWS * DD; // NCOLS*DD shorts
  float* o   = (float*)d_out;

  conv_x<<<(MROWS * DD) / 4 / 256, 256, 0, stream>>>(x, xbf);
  conv_w<<<(NCOLS * DD) / 256, 256, 0, stream>>>(Wq, Wk, Wv, wbf);
  qkv_gemm<<<(MROWS / 128) * (NCOLS / 128), 256, 0, stream>>>(xbf, wbf, qkv);
  attn_kernel<<<48 * 64, 256, 0, stream>>>(ws, o);
}

// Round 6
// 181.048 us; speedup vs baseline: 40.6551x; 1.2676x over previous
//
#include <hip/hip_runtime.h>
#include <math.h>

#define BB 4
#define SS 2048
#define DD 768
#define HH 12
#define KK 64

#define NPROJ 3
#define HK    (HH * KK)          // 768
#define NCOLS (NPROJ * HK)       // 2304
#define MROWS (BB * SS)          // 8192
#define PER   (BB * HH * SS * KK)  // 6291456 elements per proj

typedef __attribute__((ext_vector_type(8))) short bf16x8;
typedef __attribute__((ext_vector_type(4))) short bf16x4;
typedef __attribute__((ext_vector_type(4))) float f32x4;
typedef __attribute__((ext_vector_type(16))) float f32x16;

static __device__ __forceinline__ short f2bf(float f) {
  union { float f; unsigned u; } v;
  v.f = f;
  unsigned r = (v.u + 0x7fff + ((v.u >> 16) & 1)) >> 16;  // RNE
  return (short)r;
}

static __device__ __forceinline__ unsigned cvtpk(float lo, float hi) {
  unsigned r;
  asm("v_cvt_pk_bf16_f32 %0, %1, %2" : "=v"(r) : "v"(lo), "v"(hi));
  return r;
}

// ---------------------------------------------------------------------------
// x (fp32) -> bf16, flat copy. 4 elems/thread.
// ---------------------------------------------------------------------------
__global__ __launch_bounds__(256) void conv_x(const float* __restrict__ x,
                                              short* __restrict__ xbf) {
  int i = (blockIdx.x * 256 + threadIdx.x) * 4;
  float4 v = *(const float4*)(x + i);
  bf16x4 o = {f2bf(v.x), f2bf(v.y), f2bf(v.z), f2bf(v.w)};
  *(bf16x4*)(xbf + i) = o;
}

// ---------------------------------------------------------------------------
// W (3 x [H][D][K] fp32) -> bf16 transposed wT[n][d], n = proj*768 + h*64 + k.
// Q-scale 1/sqrt(64) folded into proj 0.
// ---------------------------------------------------------------------------
__global__ __launch_bounds__(256) void conv_w(const float* __restrict__ Wq,
                                              const float* __restrict__ Wk,
                                              const float* __restrict__ Wv,
                                              short* __restrict__ wbf) {
  int o = blockIdx.x * 256 + threadIdx.x;  // 2304*768 total
  int n = o / DD, d = o % DD;
  int proj = n / HK;
  int hk = n % HK;
  int h = hk >> 6, k = hk & 63;
  const float* W = proj == 0 ? Wq : (proj == 1 ? Wk : Wv);
  float v = W[(size_t)h * DD * KK + (size_t)d * KK + k];
  if (proj == 0) v *= 0.125f;
  wbf[o] = f2bf(v);
}

// ---------------------------------------------------------------------------
// QKV GEMM (unchanged): C[m][n] = sum_d xbf[m][d] * wT[n][d].
// V (proj 2) written TRANSPOSED: Vt[bh][k][s].
// ---------------------------------------------------------------------------
__global__ __launch_bounds__(256) void qkv_gemm(const short* __restrict__ xbf,
                                                const short* __restrict__ wbf,
                                                short* __restrict__ qkv) {
  __shared__ short As[128 * 64];
  __shared__ short Bs[128 * 64];
  int bm = blockIdx.x & 63, bn = blockIdx.x >> 6;
  int m0 = bm * 128, n0 = bn * 128;
  int tid = threadIdx.x, lane = tid & 63, wid = tid >> 6;
  int li = lane & 15, lg = lane >> 4;
  int wm = wid >> 1, wn = wid & 1;

  f32x4 acc[4][4];
  #pragma unroll
  for (int mi = 0; mi < 4; ++mi)
    #pragma unroll
    for (int ni = 0; ni < 4; ++ni)
      acc[mi][ni] = (f32x4){0.f, 0.f, 0.f, 0.f};

  int rowoff = lane >> 3;
  int kp = (lane & 7) * 8;

  for (int kt = 0; kt < DD / 64; ++kt) {
    #pragma unroll
    for (int j = 0; j < 4; ++j) {
      int eb = wid * 2048 + j * 512;
      int row = (eb >> 6) + rowoff;
      __builtin_amdgcn_global_load_lds(
          (const __attribute__((address_space(1))) void*)(
              xbf + (size_t)(m0 + row) * DD + kt * 64 + kp),
          (__attribute__((address_space(3))) void*)(As + eb), 16, 0, 0);
      __builtin_amdgcn_global_load_lds(
          (const __attribute__((address_space(1))) void*)(
              wbf + (size_t)(n0 + row) * DD + kt * 64 + kp),
          (__attribute__((address_space(3))) void*)(Bs + eb), 16, 0, 0);
    }
    __syncthreads();

    #pragma unroll
    for (int kk = 0; kk < 2; ++kk) {
      bf16x8 af[4], bfr[4];
      #pragma unroll
      for (int mi = 0; mi < 4; ++mi)
        af[mi] = *(const bf16x8*)(As + (wm * 64 + mi * 16 + li) * 64 +
                                  kk * 32 + lg * 8);
      #pragma unroll
      for (int ni = 0; ni < 4; ++ni)
        bfr[ni] = *(const bf16x8*)(Bs + (wn * 64 + ni * 16 + li) * 64 +
                                   kk * 32 + lg * 8);
      #pragma unroll
      for (int mi = 0; mi < 4; ++mi)
        #pragma unroll
        for (int ni = 0; ni < 4; ++ni)
          acc[mi][ni] = __builtin_amdgcn_mfma_f32_16x16x32_bf16(
              af[mi], bfr[ni], acc[mi][ni], 0, 0, 0);
    }
    __syncthreads();
  }

  int proj = n0 / HK;
  #pragma unroll
  for (int ni = 0; ni < 4; ++ni) {
    int ncol = n0 + wn * 64 + ni * 16 + li;
    int hk = ncol % HK;
    int h = hk >> 6, k = hk & 63;
    #pragma unroll
    for (int mi = 0; mi < 4; ++mi) {
      int mrow0 = m0 + wm * 64 + mi * 16 + lg * 4;
      int b = mrow0 >> 11, s = mrow0 & 2047;
      if (proj == 2) {
        bf16x4 o = {f2bf(acc[mi][ni][0]), f2bf(acc[mi][ni][1]),
                    f2bf(acc[mi][ni][2]), f2bf(acc[mi][ni][3])};
        *(bf16x4*)(qkv + 2 * (size_t)PER +
                   ((size_t)(b * HH + h) * KK + k) * SS + s) = o;
      } else {
        #pragma unroll
        for (int r = 0; r < 4; ++r)
          qkv[(size_t)proj * PER +
              ((size_t)(b * HH + h) * SS + s + r) * KK + k] =
              f2bf(acc[mi][ni][r]);
      }
    }
  }
}

// ---------------------------------------------------------------------------
// Flash attention, 32x32 MFMA, intra-block 4-way split-K.
// Block = one 32-query group; wave w handles 32-key tiles tt = w, w+4, ...
// QK^T swapped (A=K, B=Q): sc C-layout col=lane&31=q, row=key=crow(r,hi).
// PV as O^T = V^T P^T: both P-frag (from cvt_pk+permlane32_swap) and acc
// keep q = lane&31 lane-local. Only diagonal tile (tt==qg) is masked.
// Partials merged via LDS (flash-decode combine).
// ---------------------------------------------------------------------------
__global__ __launch_bounds__(256) void attn_kernel(
    const short* __restrict__ qkv, float* __restrict__ out) {
  __shared__ float accL[4][32][68];
  __shared__ float mlL[4][2][32];

  int wid = threadIdx.x >> 6, lane = threadIdx.x & 63;
  int bh = blockIdx.x % 48;          // qg-major: heaviest groups first
  int qg = 63 - (blockIdx.x / 48);
  int b = bh / HH, h = bh % HH;
  int s0 = qg * 32;
  int lq = lane & 31;                // query column
  int hi = lane >> 5;

  const short* Qb = qkv + (size_t)bh * SS * KK;
  const short* Kb = qkv + (size_t)PER + (size_t)bh * SS * KK;
  const short* Vt = qkv + 2 * (size_t)PER + (size_t)bh * KK * SS;

  // Q fragments (B operand): lane holds Q[s0+lq][c*16 + hi*8 + e]
  bf16x8 qf[4];
  #pragma unroll
  for (int c = 0; c < 4; ++c)
    qf[c] = *(const bf16x8*)(Qb + (size_t)(s0 + lq) * KK + c * 16 + hi * 8);

  f32x16 accO[2];
  #pragma unroll
  for (int m2 = 0; m2 < 2; ++m2)
    #pragma unroll
    for (int r = 0; r < 16; ++r) accO[m2][r] = 0.f;
  float m = -INFINITY, lsum = 0.f;

  for (int tt = wid; tt <= qg; tt += 4) {
    int t0 = tt * 32;
    // K fragments (A operand): lane holds K[t0+lq][c*16 + hi*8 + e]
    bf16x8 kf[4];
    #pragma unroll
    for (int c = 0; c < 4; ++c)
      kf[c] = *(const bf16x8*)(Kb + (size_t)(t0 + lq) * KK + c * 16 + hi * 8);
    // V fragments (A of O^T): lane holds Vt[32*m2+lq][t0 + c*16 + hi*8 + e]
    bf16x8 vf[2][2];
    #pragma unroll
    for (int m2 = 0; m2 < 2; ++m2)
      #pragma unroll
      for (int c = 0; c < 2; ++c)
        vf[m2][c] = *(const bf16x8*)(Vt + (size_t)(32 * m2 + lq) * SS + t0 +
                                     c * 16 + hi * 8);

    f32x16 sc;
    #pragma unroll
    for (int r = 0; r < 16; ++r) sc[r] = 0.f;
    #pragma unroll
    for (int c = 0; c < 4; ++c)
      sc = __builtin_amdgcn_mfma_f32_32x32x16_bf16(kf[c], qf[c], sc, 0, 0, 0);

    if (tt == qg) {  // diagonal tile: mask key=crow(r,hi) > q=lq
      #pragma unroll
      for (int r = 0; r < 16; ++r) {
        int crow = (r & 3) + 8 * (r >> 2) + 4 * hi;
        if (crow > lq) sc[r] = -INFINITY;
      }
    }

    float tm = sc[0];
    #pragma unroll
    for (int r = 1; r < 16; ++r) tm = fmaxf(tm, sc[r]);
    tm = fmaxf(tm, __shfl_xor(tm, 32, 64));
    if (!__all(tm <= m + 8.f)) {  // defer-max
      float nm = fmaxf(m, tm);
      float corr = __expf(m - nm);
      m = nm;
      lsum *= corr;
      #pragma unroll
      for (int m2 = 0; m2 < 2; ++m2)
        #pragma unroll
        for (int r = 0; r < 16; ++r) accO[m2][r] *= corr;
    }

    float p[16];
    float ps = 0.f;
    #pragma unroll
    for (int r = 0; r < 16; ++r) {
      p[r] = __expf(sc[r] - m);
      ps += p[r];
    }
    ps += __shfl_xor(ps, 32, 64);
    lsum += ps;

    // P fragments (B of O^T): per chunk c, words via cvt_pk + permlane32_swap
    bf16x8 pf[2];
    #pragma unroll
    for (int c = 0; c < 2; ++c) {
      unsigned a0 = cvtpk(p[8 * c + 0], p[8 * c + 1]);
      unsigned b0 = cvtpk(p[8 * c + 4], p[8 * c + 5]);
      unsigned a1 = cvtpk(p[8 * c + 2], p[8 * c + 3]);
      unsigned b1 = cvtpk(p[8 * c + 6], p[8 * c + 7]);
      asm volatile("v_permlane32_swap_b32 %0, %1" : "+v"(a0), "+v"(b0));
      asm volatile("v_permlane32_swap_b32 %0, %1" : "+v"(a1), "+v"(b1));
      union { unsigned u[4]; bf16x8 v; } pu;
      pu.u[0] = a0; pu.u[1] = a1; pu.u[2] = b0; pu.u[3] = b1;
      pf[c] = pu.v;
    }

    #pragma unroll
    for (int m2 = 0; m2 < 2; ++m2)
      #pragma unroll
      for (int c = 0; c < 2; ++c)
        accO[m2] = __builtin_amdgcn_mfma_f32_32x32x16_bf16(vf[m2][c], pf[c],
                                                           accO[m2], 0, 0, 0);
  }

  // ---- write partials: acc q=lq, kd=32*m2+crow(r,hi) ----
  #pragma unroll
  for (int m2 = 0; m2 < 2; ++m2)
    #pragma unroll
    for (int g = 0; g < 4; ++g) {
      f32x4 v = {accO[m2][g * 4 + 0], accO[m2][g * 4 + 1],
                 accO[m2][g * 4 + 2], accO[m2][g * 4 + 3]};
      *(f32x4*)&accL[wid][lq][32 * m2 + 8 * g + 4 * hi] = v;
    }
  if (hi == 0) {
    mlL[wid][0][lq] = m;
    mlL[wid][1][lq] = lsum;
  }
  __syncthreads();

  // ---- merge (flash-decode combine): wave w -> queries 8w..8w+7 ----
  {
    int q = 8 * wid + (lane >> 3);
    int kd = (lane & 7) * 8;
    float M = -INFINITY;
    #pragma unroll
    for (int v = 0; v < 4; ++v) M = fmaxf(M, mlL[v][0][q]);
    float scw[4], L = 0.f;
    #pragma unroll
    for (int v = 0; v < 4; ++v) {
      scw[v] = __expf(mlL[v][0][q] - M);
      L += mlL[v][1][q] * scw[v];
    }
    float inv = 1.0f / L;
    float o[8];
    #pragma unroll
    for (int j = 0; j < 8; ++j) o[j] = 0.f;
    #pragma unroll
    for (int v = 0; v < 4; ++v) {
      f32x4 a0 = *(const f32x4*)&accL[v][q][kd];
      f32x4 a1 = *(const f32x4*)&accL[v][q][kd + 4];
      #pragma unroll
      for (int j = 0; j < 4; ++j) {
        o[j] += a0[j] * scw[v];
        o[4 + j] += a1[j] * scw[v];
      }
    }
    float* orow = out + ((size_t)(b * SS + s0 + q)) * HK + h * KK + kd;
    float4 w0 = {o[0] * inv, o[1] * inv, o[2] * inv, o[3] * inv};
    float4 w1 = {o[4] * inv, o[5] * inv, o[6] * inv, o[7] * inv};
    *(float4*)(orow) = w0;
    *(float4*)(orow + 4) = w1;
  }
}

// ---------------------------------------------------------------------------
extern "C" void kernel_launch(void* const* d_in, const int* in_sizes, int n_in,
                              void* d_out, int out_size, void* d_ws,
                              size_t ws_size, hipStream_t stream) {
  const float* x  = (const float*)d_in[0];
  const float* Wq = (const float*)d_in[1];
  const float* Wk = (const float*)d_in[2];
  const float* Wv = (const float*)d_in[3];
  short* ws  = (short*)d_ws;
  short* qkv = ws;                       // 3 * PER shorts
  short* xbf = ws + (size_t)3 * PER;     // MROWS*DD shorts
  short* wbf = xbf + (size_t)MROWS * DD; // NCOLS*DD shorts
  float* o   = (float*)d_out;

  conv_x<<<(MROWS * DD) / 4 / 256, 256, 0, stream>>>(x, xbf);
  conv_w<<<(NCOLS * DD) / 256, 256, 0, stream>>>(Wq, Wk, Wv, wbf);
  qkv_gemm<<<(MROWS / 128) * (NCOLS / 128), 256, 0, stream>>>(xbf, wbf, qkv);
  attn_kernel<<<48 * 64, 256, 0, stream>>>(ws, o);
}